// Round 2
// baseline (157.283 us; speedup 1.0000x reference)
//
#include <hip/hip_runtime.h>

// Problem: n=16, c=256, h=w=64.  nc = 4096 independent 64x64 tiles.
// per tile: A = softmax over h of X^T  (A[wi][h], i.e. column-softmax of X)
//           Xn = rowwise layernorm (unbiased std, eps added to std)
//           node = A @ Xn ; out = relu(node @ W)
#define PAD 68   // row stride in floats: 68*4=272B (16B aligned), 68%32=4

__global__ __launch_bounds__(256, 2)
void gnn_fused(const float* __restrict__ X, const float* __restrict__ W,
               const float* __restrict__ a2, const float* __restrict__ b2,
               float* __restrict__ out)
{
    __shared__ float Xs[64 * PAD];   // X tile, later overwritten by Xn (in place)
    __shared__ float AT[64 * PAD];   // A^T[h][wi], later overwritten by node^T[k][r]
    __shared__ float Ws[64 * PAD];   // W[k][j]
    __shared__ float a2s[64], b2s[64];

    const int tid = threadIdx.x;
    const int b   = blockIdx.x;
    const float* Xb = X + (size_t)b * 4096;

    // ---- phase 0: load X and W into LDS (float4, coalesced) ----
    #pragma unroll
    for (int i = 0; i < 4; ++i) {
        int f4  = tid + i * 256;        // float4 index 0..1023
        int row = f4 >> 4;              // 16 float4 per 64-wide row
        int col = (f4 & 15) << 2;
        float4 v  = ((const float4*)Xb)[f4];
        float4 wv = ((const float4*)W)[f4];
        *(float4*)&Xs[row * PAD + col] = v;
        *(float4*)&Ws[row * PAD + col] = wv;
    }
    if (tid < 64) { a2s[tid] = a2[tid]; b2s[tid] = b2[tid]; }
    __syncthreads();

    // ---- phase 1: column softmax -> AT[h][col] ----
    {
        const int col = tid >> 2;           // 0..63
        const int h0  = (tid & 3) << 4;     // 0,16,32,48
        float v[16];
        float m = -3.402823466e+38f;
        #pragma unroll
        for (int i = 0; i < 16; ++i) {
            v[i] = Xs[(h0 + i) * PAD + col];
            m = fmaxf(m, v[i]);
        }
        m = fmaxf(m, __shfl_xor(m, 1));
        m = fmaxf(m, __shfl_xor(m, 2));
        float s = 0.f;
        #pragma unroll
        for (int i = 0; i < 16; ++i) { v[i] = __expf(v[i] - m); s += v[i]; }
        s += __shfl_xor(s, 1);
        s += __shfl_xor(s, 2);
        const float inv = 1.0f / s;
        #pragma unroll
        for (int i = 0; i < 16; ++i) AT[(h0 + i) * PAD + col] = v[i] * inv;
    }
    __syncthreads();

    // ---- phase 2: row layernorm, Xs in place ----
    {
        const int row = tid >> 2;
        const int c0  = (tid & 3) << 4;
        float v[16];
        float s = 0.f, sq = 0.f;
        #pragma unroll
        for (int i = 0; i < 16; ++i) {
            v[i] = Xs[row * PAD + c0 + i];
            s  += v[i];
            sq += v[i] * v[i];
        }
        s  += __shfl_xor(s, 1);  s  += __shfl_xor(s, 2);
        sq += __shfl_xor(sq, 1); sq += __shfl_xor(sq, 2);
        const float mean = s * (1.0f / 64.0f);
        float var = (sq - 64.0f * mean * mean) * (1.0f / 63.0f);
        var = fmaxf(var, 0.0f);
        const float invstd = 1.0f / (sqrtf(var) + 1e-6f);
        #pragma unroll
        for (int i = 0; i < 16; ++i) {
            const int c = c0 + i;
            Xs[row * PAD + c] = a2s[c] * (v[i] - mean) * invstd + b2s[c];
        }
    }
    __syncthreads();

    // thread tile mapping: 16x16 thread grid, each owns a 4x4 output tile
    const int ti = tid >> 4;    // 0..15  (row-group of the tile this thread owns)
    const int tj = tid & 15;    // 0..15  (col-group)

    // ---- phase 3: nodeT[R][C] = sum_h Xn[h][R] * AT[h][C] ----
    // (computing node TRANSPOSED so phase 4 reads it contiguously)
    float acc[4][4];
    #pragma unroll
    for (int i = 0; i < 4; ++i)
        #pragma unroll
        for (int j = 0; j < 4; ++j) acc[i][j] = 0.f;

    #pragma unroll 8
    for (int k = 0; k < 64; ++k) {
        float4 xv = *(const float4*)&Xs[k * PAD + 4 * ti];  // Xn[k][4ti..]
        float4 av = *(const float4*)&AT[k * PAD + 4 * tj];  // AT[k][4tj..]
        const float xr[4] = {xv.x, xv.y, xv.z, xv.w};
        const float ar[4] = {av.x, av.y, av.z, av.w};
        #pragma unroll
        for (int i = 0; i < 4; ++i)
            #pragma unroll
            for (int j = 0; j < 4; ++j) acc[i][j] += xr[i] * ar[j];
    }
    __syncthreads();   // everyone done reading AT
    #pragma unroll
    for (int i = 0; i < 4; ++i) {
        float4 v = make_float4(acc[i][0], acc[i][1], acc[i][2], acc[i][3]);
        *(float4*)&AT[(4 * ti + i) * PAD + 4 * tj] = v;   // node^T
    }
    __syncthreads();

    // ---- phase 4: out[R][C] = relu( sum_k nodeT[k][R] * W[k][C] ) ----
    float acc2[4][4];
    #pragma unroll
    for (int i = 0; i < 4; ++i)
        #pragma unroll
        for (int j = 0; j < 4; ++j) acc2[i][j] = 0.f;

    #pragma unroll 8
    for (int k = 0; k < 64; ++k) {
        float4 nv = *(const float4*)&AT[k * PAD + 4 * ti];  // nodeT[k][4ti..]
        float4 wv = *(const float4*)&Ws[k * PAD + 4 * tj];  // W[k][4tj..]
        const float nr[4] = {nv.x, nv.y, nv.z, nv.w};
        const float wr[4] = {wv.x, wv.y, wv.z, wv.w};
        #pragma unroll
        for (int i = 0; i < 4; ++i)
            #pragma unroll
            for (int j = 0; j < 4; ++j) acc2[i][j] += nr[i] * wr[j];
    }

    float* outb = out + (size_t)b * 4096;
    #pragma unroll
    for (int i = 0; i < 4; ++i) {
        float4 v;
        v.x = fmaxf(acc2[i][0], 0.f);
        v.y = fmaxf(acc2[i][1], 0.f);
        v.z = fmaxf(acc2[i][2], 0.f);
        v.w = fmaxf(acc2[i][3], 0.f);
        *(float4*)&outb[(4 * ti + i) * 64 + 4 * tj] = v;
    }
}

extern "C" void kernel_launch(void* const* d_in, const int* in_sizes, int n_in,
                              void* d_out, int out_size, void* d_ws, size_t ws_size,
                              hipStream_t stream) {
    const float* X  = (const float*)d_in[0];
    const float* W  = (const float*)d_in[1];
    const float* a2 = (const float*)d_in[2];
    const float* b2 = (const float*)d_in[3];
    float* out = (float*)d_out;
    gnn_fused<<<4096, 256, 0, stream>>>(X, W, a2, b2, out);
}

// Round 3
// 136.603 us; speedup vs baseline: 1.1514x; 1.1514x over previous
//
#include <hip/hip_runtime.h>

// n=16,c=256,h=w=64 -> 4096 independent 64x64 tiles.
// A = softmax_h(X^T) [wi][h]; Xn = rowwise LN(X) (unbiased std, eps on std);
// node = A@Xn; out = relu(node@W).
// MFMA 32x32x16_bf16, hi/lo split (3 mfma per k-step) for f32-grade accuracy.

typedef __attribute__((ext_vector_type(8)))  short  s16x8;   // 8 bf16 (A/B frag)
typedef __attribute__((ext_vector_type(16))) float  f32x16;  // C/D frag
typedef __attribute__((ext_vector_type(8)))  unsigned short us8;

__device__ __forceinline__ unsigned short f2bf(float x) {   // RNE f32->bf16 (finite)
    unsigned u = __builtin_bit_cast(unsigned, x);
    u += 0x7FFFu + ((u >> 16) & 1u);
    return (unsigned short)(u >> 16);
}
__device__ __forceinline__ float bf2f(unsigned short h) {
    unsigned u = ((unsigned)h) << 16;
    return __builtin_bit_cast(float, u);
}
// swizzled ushort index into [64 rows][64 k] bf16 buffer (128B rows):
// XOR bits 3..5 of k with row&7 -> b128 column reads spread across 8 slots
__device__ __forceinline__ int swidx(int row, int k) {
    return row * 64 + (k ^ ((row & 7) << 3));
}

__global__ __launch_bounds__(256, 3)
void gnn_mfma(const float* __restrict__ X, const float* __restrict__ Wg,
              const float* __restrict__ a2, const float* __restrict__ b2,
              float* __restrict__ out)
{
    // 3 x 16KB = 48KB -> 3 blocks/CU
    __shared__ __align__(16) unsigned short bufA[2][64 * 64]; // A[w1][h], later node[w1][w2]
    __shared__ __align__(16) unsigned short bufX[2][64 * 64]; // XnT[w2][h]
    __shared__ __align__(16) unsigned short bufW[2][64 * 64]; // WT[j][w2]

    const int tid = threadIdx.x;
    const int b   = blockIdx.x;
    const float* xb = X + (size_t)b * 4096;

    // ---- phase 1: column softmax -> A[wi][h] (bf16 hi/lo, swizzled) ----
    {
        const int wi = tid >> 2;            // 0..63
        const int h0 = (tid & 3) << 4;      // 0,16,32,48
        float v[16];
        #pragma unroll
        for (int i = 0; i < 16; ++i) v[i] = xb[(h0 + i) * 64 + wi];
        float m = v[0];
        #pragma unroll
        for (int i = 1; i < 16; ++i) m = fmaxf(m, v[i]);
        m = fmaxf(m, __shfl_xor(m, 1));
        m = fmaxf(m, __shfl_xor(m, 2));
        float s = 0.f;
        #pragma unroll
        for (int i = 0; i < 16; ++i) { v[i] = __expf(v[i] - m); s += v[i]; }
        s += __shfl_xor(s, 1);
        s += __shfl_xor(s, 2);
        const float inv = 1.0f / s;
        us8 hv0, lv0, hv1, lv1;
        #pragma unroll
        for (int i = 0; i < 8; ++i) {
            float p = v[i] * inv;
            unsigned short hh = f2bf(p);
            hv0[i] = hh; lv0[i] = f2bf(p - bf2f(hh));
        }
        #pragma unroll
        for (int i = 0; i < 8; ++i) {
            float p = v[8 + i] * inv;
            unsigned short hh = f2bf(p);
            hv1[i] = hh; lv1[i] = f2bf(p - bf2f(hh));
        }
        const int sw = (wi & 7) << 3;
        const int i0 = wi * 64 + (h0 ^ sw);
        const int i1 = wi * 64 + ((h0 + 8) ^ sw);
        *(us8*)&bufA[0][i0] = hv0; *(us8*)&bufA[0][i1] = hv1;
        *(us8*)&bufA[1][i0] = lv0; *(us8*)&bufA[1][i1] = lv1;
    }

    // ---- phase 2: row layernorm -> XnT[w][h] (transposed scalar writes) ----
    {
        const int h  = tid >> 2;            // 0..63
        const int c0 = (tid & 3) << 4;      // 0,16,32,48
        float x[16];
        #pragma unroll
        for (int i = 0; i < 4; ++i) {
            float4 t = *(const float4*)&xb[h * 64 + c0 + 4 * i];
            x[4 * i] = t.x; x[4 * i + 1] = t.y; x[4 * i + 2] = t.z; x[4 * i + 3] = t.w;
        }
        float s = 0.f, sq = 0.f;
        #pragma unroll
        for (int i = 0; i < 16; ++i) { s += x[i]; sq += x[i] * x[i]; }
        s  += __shfl_xor(s, 1);  s  += __shfl_xor(s, 2);
        sq += __shfl_xor(sq, 1); sq += __shfl_xor(sq, 2);
        const float mean = s * (1.0f / 64.0f);
        float var = (sq - 64.0f * mean * mean) * (1.0f / 63.0f);
        var = fmaxf(var, 0.0f);
        const float invstd = 1.0f / (sqrtf(var) + 1e-6f);
        float av[16], bv[16];
        #pragma unroll
        for (int i = 0; i < 4; ++i) {
            float4 ta = *(const float4*)&a2[c0 + 4 * i];
            float4 tb = *(const float4*)&b2[c0 + 4 * i];
            av[4*i] = ta.x; av[4*i+1] = ta.y; av[4*i+2] = ta.z; av[4*i+3] = ta.w;
            bv[4*i] = tb.x; bv[4*i+1] = tb.y; bv[4*i+2] = tb.z; bv[4*i+3] = tb.w;
        }
        #pragma unroll
        for (int i = 0; i < 16; ++i) {
            float xn = av[i] * (x[i] - mean) * invstd + bv[i];
            unsigned short hh = f2bf(xn);
            const int idx = swidx(c0 + i, h);
            bufX[0][idx] = hh;
            bufX[1][idx] = f2bf(xn - bf2f(hh));
        }
    }

    // ---- phase W: W^T -> WT[j][w2] (coalesced row reads, contiguous writes) ----
    {
        const int j = tid & 63;
        const int q = tid >> 6;             // wave id -> w2 quarter
        float wv[16];
        #pragma unroll
        for (int i = 0; i < 16; ++i) wv[i] = Wg[(16 * q + i) * 64 + j];
        us8 hv0, lv0, hv1, lv1;
        #pragma unroll
        for (int i = 0; i < 8; ++i) {
            unsigned short hh = f2bf(wv[i]);
            hv0[i] = hh; lv0[i] = f2bf(wv[i] - bf2f(hh));
        }
        #pragma unroll
        for (int i = 0; i < 8; ++i) {
            unsigned short hh = f2bf(wv[8 + i]);
            hv1[i] = hh; lv1[i] = f2bf(wv[8 + i] - bf2f(hh));
        }
        const int sw = (j & 7) << 3;
        const int i0 = j * 64 + ((16 * q) ^ sw);
        const int i1 = j * 64 + ((16 * q + 8) ^ sw);
        *(us8*)&bufW[0][i0] = hv0; *(us8*)&bufW[0][i1] = hv1;
        *(us8*)&bufW[1][i0] = lv0; *(us8*)&bufW[1][i1] = lv1;
    }
    __syncthreads();

    // ---- matmul 1: node = A @ Xn (each wave one 32x32 tile) ----
    const int wid  = tid >> 6;
    const int lane = tid & 63;
    const int r    = lane & 31;
    const int hl   = lane >> 5;
    const int R = (wid & 1) * 32;     // output row base (w1)
    const int C = (wid >> 1) * 32;    // output col base (w2 / j)

    f32x16 acc;
    #pragma unroll
    for (int i = 0; i < 16; ++i) acc[i] = 0.f;

    const int rowA = R + r;   // A row = w1
    const int rowB = C + r;   // XnT row = w2
    #pragma unroll
    for (int t = 0; t < 4; ++t) {
        const int k0 = 16 * t + 8 * hl;
        s16x8 aH = *(const s16x8*)&bufA[0][rowA * 64 + (k0 ^ ((rowA & 7) << 3))];
        s16x8 aL = *(const s16x8*)&bufA[1][rowA * 64 + (k0 ^ ((rowA & 7) << 3))];
        s16x8 bH = *(const s16x8*)&bufX[0][rowB * 64 + (k0 ^ ((rowB & 7) << 3))];
        s16x8 bL = *(const s16x8*)&bufX[1][rowB * 64 + (k0 ^ ((rowB & 7) << 3))];
        acc = __builtin_amdgcn_mfma_f32_32x32x16_bf16(aH, bH, acc, 0, 0, 0);
        acc = __builtin_amdgcn_mfma_f32_32x32x16_bf16(aH, bL, acc, 0, 0, 0);
        acc = __builtin_amdgcn_mfma_f32_32x32x16_bf16(aL, bH, acc, 0, 0, 0);
    }
    __syncthreads();   // all reads of A/XnT done -> bufA reusable for node

    // write node[w1][w2] (bf16 hi/lo, swizzled) over bufA
    #pragma unroll
    for (int g = 0; g < 16; ++g) {
        const int w1 = R + (g & 3) + 8 * (g >> 2) + 4 * hl;  // C/D row (m74/m101)
        const float xv = acc[g];
        const unsigned short hh = f2bf(xv);
        const int idx = swidx(w1, C + r);
        bufA[0][idx] = hh;
        bufA[1][idx] = f2bf(xv - bf2f(hh));
    }
    __syncthreads();

    // ---- matmul 2: out = relu(node @ W) ----
    f32x16 acc2;
    #pragma unroll
    for (int i = 0; i < 16; ++i) acc2[i] = 0.f;

    const int rowN = R + r;   // node row = w1
    const int rowW = C + r;   // WT row = j
    #pragma unroll
    for (int t = 0; t < 4; ++t) {
        const int k0 = 16 * t + 8 * hl;
        s16x8 nH = *(const s16x8*)&bufA[0][rowN * 64 + (k0 ^ ((rowN & 7) << 3))];
        s16x8 nL = *(const s16x8*)&bufA[1][rowN * 64 + (k0 ^ ((rowN & 7) << 3))];
        s16x8 wH = *(const s16x8*)&bufW[0][rowW * 64 + (k0 ^ ((rowW & 7) << 3))];
        s16x8 wL = *(const s16x8*)&bufW[1][rowW * 64 + (k0 ^ ((rowW & 7) << 3))];
        acc2 = __builtin_amdgcn_mfma_f32_32x32x16_bf16(nH, wH, acc2, 0, 0, 0);
        acc2 = __builtin_amdgcn_mfma_f32_32x32x16_bf16(nH, wL, acc2, 0, 0, 0);
        acc2 = __builtin_amdgcn_mfma_f32_32x32x16_bf16(nL, wH, acc2, 0, 0, 0);
    }

    float* ob = out + (size_t)b * 4096;
    #pragma unroll
    for (int g = 0; g < 16; ++g) {
        const int w1 = R + (g & 3) + 8 * (g >> 2) + 4 * hl;
        ob[w1 * 64 + C + r] = fmaxf(acc2[g], 0.f);
    }
}

extern "C" void kernel_launch(void* const* d_in, const int* in_sizes, int n_in,
                              void* d_out, int out_size, void* d_ws, size_t ws_size,
                              hipStream_t stream) {
    const float* X  = (const float*)d_in[0];
    const float* W  = (const float*)d_in[1];
    const float* a2 = (const float*)d_in[2];
    const float* b2 = (const float*)d_in[3];
    float* out = (float*)d_out;
    gnn_mfma<<<4096, 256, 0, stream>>>(X, W, a2, b2, out);
}

// Round 4
// 131.234 us; speedup vs baseline: 1.1985x; 1.0409x over previous
//
#include <hip/hip_runtime.h>
#include <hip/hip_bf16.h>

// n=16,c=256,h=w=64 -> 4096 independent 64x64 tiles.
// A = softmax_h(X^T); Xn = rowwise LN(X) (unbiased std, eps on std);
// node = A@Xn; out = relu(node@W).
// MFMA 32x32x16_bf16. Split precision: A=hi only (A in [0,1], sum 1);
// Xn, W, node = hi/lo bf16 pairs. 20 MFMAs/wave.

typedef __attribute__((ext_vector_type(8)))  short  s16x8;   // MFMA A/B frag
typedef __attribute__((ext_vector_type(16))) float  f32x16;  // MFMA C/D frag
typedef __attribute__((ext_vector_type(8)))  unsigned short us8;

__device__ __forceinline__ unsigned short f2bf(float x) {   // RNE via v_cvt (compiler packs)
    __hip_bfloat16 b = __float2bfloat16(x);
    return __builtin_bit_cast(unsigned short, b);
}
__device__ __forceinline__ float bf2f(unsigned short h) {
    unsigned u = ((unsigned)h) << 16;
    return __builtin_bit_cast(float, u);
}
// swizzle: spreads BOTH the 32-consecutive-row b128 MFMA reads (8 quads,
// balanced) AND the LN strided b16 writes (rows {i,16+i,32+i,48+i} -> 4
// distinct sw values -> 32 banks, 2-way = free). Old (row&7)<<3 was 8-way
// on LN writes (all four c0 groups share row&7).
__device__ __forceinline__ int swz(int row) {
    return ((row & 7) ^ ((row >> 3) & 7)) << 3;
}
__device__ __forceinline__ int swidx(int row, int k) {
    return row * 64 + (k ^ swz(row));
}

// one-time W -> WT[j][k] bf16 hi/lo, swizzled, into ws (runs every launch)
__global__ void prep_w(const float* __restrict__ Wg, unsigned short* __restrict__ ws) {
    const int gid = blockIdx.x * 256 + threadIdx.x;  // 0..4095
    const int j = gid & 63;          // col of W
    const int k = gid >> 6;          // row of W
    const float x = Wg[k * 64 + j];  // coalesced over j
    const unsigned short hh = f2bf(x);
    const unsigned short ll = f2bf(x - bf2f(hh));
    const int idx = swidx(j, k);     // WT layout [j][k]
    ws[idx] = hh;
    ws[4096 + idx] = ll;
}

__global__ __launch_bounds__(256, 4)
void gnn_mfma(const float* __restrict__ X, const unsigned short* __restrict__ Wp,
              const float* __restrict__ a2, const float* __restrict__ b2,
              float* __restrict__ out)
{
    // 8KB + 16KB + 16KB = 40960B exactly -> 4 blocks/CU
    __shared__ __align__(16) unsigned short bufA[64 * 64];     // A hi; later node hi
    __shared__ __align__(16) unsigned short bufX[2][64 * 64];  // XnT hi/lo; [0] later node lo
    __shared__ __align__(16) unsigned short bufW[2][64 * 64];  // WT hi/lo

    const int tid = threadIdx.x;
    const int b   = blockIdx.x;
    const float* xb = X + (size_t)b * 4096;

    // ---- phase W: linear copy of precomputed WT hi/lo into LDS ----
    {
        const us8* src = (const us8*)Wp;
        us8* dh = (us8*)bufW[0];
        us8* dl = (us8*)bufW[1];
        dh[2 * tid]     = src[2 * tid];
        dh[2 * tid + 1] = src[2 * tid + 1];
        dl[2 * tid]     = src[512 + 2 * tid];
        dl[2 * tid + 1] = src[512 + 2 * tid + 1];
    }

    // ---- phase 1: column softmax -> A[wi][h] (hi only, swizzled) ----
    {
        const int wi = tid >> 2;            // 0..63
        const int h0 = (tid & 3) << 4;      // 0,16,32,48
        float v[16];
        #pragma unroll
        for (int i = 0; i < 16; ++i) v[i] = xb[(h0 + i) * 64 + wi];
        float m = v[0];
        #pragma unroll
        for (int i = 1; i < 16; ++i) m = fmaxf(m, v[i]);
        m = fmaxf(m, __shfl_xor(m, 1));
        m = fmaxf(m, __shfl_xor(m, 2));
        float s = 0.f;
        #pragma unroll
        for (int i = 0; i < 16; ++i) { v[i] = __expf(v[i] - m); s += v[i]; }
        s += __shfl_xor(s, 1);
        s += __shfl_xor(s, 2);
        const float inv = 1.0f / s;
        us8 hv0, hv1;
        #pragma unroll
        for (int i = 0; i < 8; ++i) hv0[i] = f2bf(v[i] * inv);
        #pragma unroll
        for (int i = 0; i < 8; ++i) hv1[i] = f2bf(v[8 + i] * inv);
        const int sw = swz(wi);
        *(us8*)&bufA[wi * 64 + (h0 ^ sw)]       = hv0;
        *(us8*)&bufA[wi * 64 + ((h0 + 8) ^ sw)] = hv1;
    }

    // ---- phase 2: row layernorm -> XnT[c][h] hi/lo (transposed b16 writes) ----
    {
        const int h  = tid >> 2;            // 0..63 (X row)
        const int c0 = (tid & 3) << 4;      // 0,16,32,48
        float x[16];
        #pragma unroll
        for (int i = 0; i < 4; ++i) {
            float4 t = *(const float4*)&xb[h * 64 + c0 + 4 * i];
            x[4 * i] = t.x; x[4 * i + 1] = t.y; x[4 * i + 2] = t.z; x[4 * i + 3] = t.w;
        }
        float s = 0.f, sq = 0.f;
        #pragma unroll
        for (int i = 0; i < 16; ++i) { s += x[i]; sq += x[i] * x[i]; }
        s  += __shfl_xor(s, 1);  s  += __shfl_xor(s, 2);
        sq += __shfl_xor(sq, 1); sq += __shfl_xor(sq, 2);
        const float mean = s * (1.0f / 64.0f);
        float var = (sq - 64.0f * mean * mean) * (1.0f / 63.0f);
        var = fmaxf(var, 0.0f);
        const float invstd = 1.0f / (sqrtf(var) + 1e-6f);
        float av[16], bv[16];
        #pragma unroll
        for (int i = 0; i < 4; ++i) {
            float4 ta = *(const float4*)&a2[c0 + 4 * i];
            float4 tb = *(const float4*)&b2[c0 + 4 * i];
            av[4*i] = ta.x; av[4*i+1] = ta.y; av[4*i+2] = ta.z; av[4*i+3] = ta.w;
            bv[4*i] = tb.x; bv[4*i+1] = tb.y; bv[4*i+2] = tb.z; bv[4*i+3] = tb.w;
        }
        #pragma unroll
        for (int i = 0; i < 16; ++i) {
            const float xn = av[i] * (x[i] - mean) * invstd + bv[i];
            const unsigned short hh = f2bf(xn);
            const int idx = swidx(c0 + i, h);
            bufX[0][idx] = hh;
            bufX[1][idx] = f2bf(xn - bf2f(hh));
        }
    }
    __syncthreads();

    // ---- matmul 1: node = A @ Xn (wave -> one 32x32 tile), 8 MFMAs ----
    const int wid  = tid >> 6;
    const int lane = tid & 63;
    const int r    = lane & 31;
    const int hl   = lane >> 5;
    const int R = (wid & 1) * 32;
    const int C = (wid >> 1) * 32;

    const int rowA = R + r;   // A row (w1)      -- also node row in mm2
    const int rowB = C + r;   // XnT row (w2)    -- also WT row (j) in mm2
    const int swA = swz(rowA);
    const int swB = swz(rowB);

    f32x16 acc;
    #pragma unroll
    for (int i = 0; i < 16; ++i) acc[i] = 0.f;

    #pragma unroll
    for (int t = 0; t < 4; ++t) {
        const int k0 = 16 * t + 8 * hl;
        s16x8 aH = *(const s16x8*)&bufA[rowA * 64 + (k0 ^ swA)];
        s16x8 bH = *(const s16x8*)&bufX[0][rowB * 64 + (k0 ^ swB)];
        s16x8 bL = *(const s16x8*)&bufX[1][rowB * 64 + (k0 ^ swB)];
        acc = __builtin_amdgcn_mfma_f32_32x32x16_bf16(aH, bH, acc, 0, 0, 0);
        acc = __builtin_amdgcn_mfma_f32_32x32x16_bf16(aH, bL, acc, 0, 0, 0);
    }
    __syncthreads();   // all mm1 reads of bufA/bufX done

    // node[w1][w2] hi -> bufA, lo -> bufX[0]
    #pragma unroll
    for (int g = 0; g < 16; ++g) {
        const int w1 = R + (g & 3) + 8 * (g >> 2) + 4 * hl;  // C/D row map (m74/m101)
        const float xv = acc[g];
        const unsigned short hh = f2bf(xv);
        const int idx = swidx(w1, C + r);
        bufA[idx]    = hh;
        bufX[0][idx] = f2bf(xv - bf2f(hh));
    }
    __syncthreads();

    // ---- matmul 2: out = relu(node @ W), 12 MFMAs ----
    f32x16 acc2;
    #pragma unroll
    for (int i = 0; i < 16; ++i) acc2[i] = 0.f;

    #pragma unroll
    for (int t = 0; t < 4; ++t) {
        const int k0 = 16 * t + 8 * hl;
        s16x8 nH = *(const s16x8*)&bufA[rowA * 64 + (k0 ^ swA)];
        s16x8 nL = *(const s16x8*)&bufX[0][rowA * 64 + (k0 ^ swA)];
        s16x8 wH = *(const s16x8*)&bufW[0][rowB * 64 + (k0 ^ swB)];
        s16x8 wL = *(const s16x8*)&bufW[1][rowB * 64 + (k0 ^ swB)];
        acc2 = __builtin_amdgcn_mfma_f32_32x32x16_bf16(nH, wH, acc2, 0, 0, 0);
        acc2 = __builtin_amdgcn_mfma_f32_32x32x16_bf16(nH, wL, acc2, 0, 0, 0);
        acc2 = __builtin_amdgcn_mfma_f32_32x32x16_bf16(nL, wH, acc2, 0, 0, 0);
    }

    float* ob = out + (size_t)b * 4096;
    #pragma unroll
    for (int g = 0; g < 16; ++g) {
        const int w1 = R + (g & 3) + 8 * (g >> 2) + 4 * hl;
        ob[w1 * 64 + C + r] = fmaxf(acc2[g], 0.f);
    }
}

extern "C" void kernel_launch(void* const* d_in, const int* in_sizes, int n_in,
                              void* d_out, int out_size, void* d_ws, size_t ws_size,
                              hipStream_t stream) {
    const float* X  = (const float*)d_in[0];
    const float* W  = (const float*)d_in[1];
    const float* a2 = (const float*)d_in[2];
    const float* b2 = (const float*)d_in[3];
    float* out = (float*)d_out;
    unsigned short* wp = (unsigned short*)d_ws;   // 16KB: WT hi[4096] + lo[4096]
    prep_w<<<16, 256, 0, stream>>>(W, wp);
    gnn_mfma<<<4096, 256, 0, stream>>>(X, wp, a2, b2, out);
}